// Round 1
// 252.270 us; speedup vs baseline: 1.0036x; 1.0036x over previous
//
#include <hip/hip_runtime.h>
#include <hip/hip_bf16.h>

typedef __attribute__((ext_vector_type(8))) short short8;
typedef __attribute__((ext_vector_type(4))) float f32x4;
typedef unsigned short u16;
typedef unsigned int u32;
typedef unsigned long long u64;

typedef u64    __attribute__((may_alias)) u64a;
typedef short8 __attribute__((may_alias)) short8a;
typedef float4 __attribute__((may_alias)) float4a;

#define Tseq 4096
#define LPP  72

__device__ __forceinline__ u32 pk_bf(float a, float b) {
    union { __hip_bfloat162 h; u32 u; } t;
    float2 f; f.x = a; f.y = b;
    t.h = __float22bfloat162_rn(f);
    return t.u;
}

__device__ __forceinline__ u16 f2bf(float f) {
    u32 u = __float_as_uint(f);
    u = (u + 0x7FFFu + ((u >> 16) & 1u)) >> 16;
    return (u16)u;
}

__device__ __forceinline__ short8 ld_frag_lds(const u16* p) {
    union { short8 v; u64 u[2]; } t;
    t.u[0] = *(const u64a*)(p);
    t.u[1] = *(const u64a*)(p + 4);
    return t.v;
}

__device__ __forceinline__ short8 cvt8(float4 a, float4 b) {
    union { short8 s; u32 u[4]; } t;
    t.u[0] = pk_bf(a.x, a.y); t.u[1] = pk_bf(a.z, a.w);
    t.u[2] = pk_bf(b.x, b.y); t.u[3] = pk_bf(b.z, b.w);
    return t.s;
}

__device__ __forceinline__ void gld_lds16(const void* g, void* l) {
    __builtin_amdgcn_global_load_lds(
        (const __attribute__((address_space(1))) u32*)g,
        (__attribute__((address_space(3))) u32*)l, 16, 0, 0);
}

// ---- W -> fragment-major bf16 (B-operand layout), 1/sqrt(C) folded into Wq ----
__global__ __launch_bounds__(256) void wt_kernel(const float* __restrict__ Wq,
                                                 const float* __restrict__ Wk,
                                                 const float* __restrict__ Wv,
                                                 u16* __restrict__ wtf) {
    int idx = blockIdx.x * 256 + threadIdx.x;
    int lane = idx & 63, cc = (idx >> 6) & 31, n = (idx >> 11) & 3, mat = idx >> 13;
    const float* W = (mat == 0) ? Wq : ((mat == 1) ? Wk : Wv);
    float sc = (mat == 0) ? 0.03125f : 1.0f;
    int h = n * 16 + (lane & 15);
    int cbase = cc * 32 + (lane >> 4) * 8;
    union { short8 s; u32 u[4]; } t;
#pragma unroll
    for (int j2 = 0; j2 < 4; ++j2) {
        float a = W[(size_t)(cbase + j2 * 2)     * 64 + h] * sc;
        float b = W[(size_t)(cbase + j2 * 2 + 1) * 64 + h] * sc;
        t.u[j2] = pk_bf(a, b);
    }
    *(short8a*)(wtf + (size_t)idx * 8) = t.s;
}

// ---- QKV projection: async-LDS W staging (double-buffered), x reg pipeline ----
__global__ __launch_bounds__(256, 2) void proj_kernel(const float* __restrict__ x,
                                                      const u16* __restrict__ wtf,
                                                      u16* __restrict__ qb,
                                                      u16* __restrict__ kA,
                                                      u16* __restrict__ vA) {
    // phase = 2 cc's; buf = 12 mn x 2 ccp x 64 lanes x 8 u16 = 24 KiB
    __shared__ __align__(16) u16 Wl[2][12 * 2 * 64 * 8];

    const int tid = threadIdx.x, lane = tid & 63, wave = tid >> 6;
    const int m = lane & 15, quad = lane >> 4;
    const long rowbase = (long)blockIdx.x * 64 + wave * 16;
    const float* xr = x + (rowbase + m) * 1024 + quad * 8;

    f32x4 acc[12];
#pragma unroll
    for (int i = 0; i < 12; ++i) acc[i] = (f32x4){0.f, 0.f, 0.f, 0.f};

    // stage phase p into Wl[buf]: 24 chunks of 1 KiB; this wave does 6
#define STAGE(p, buf)                                                          \
    {                                                                          \
        _Pragma("unroll")                                                      \
        for (int i = 0; i < 6; ++i) {                                          \
            int c = wave * 6 + i, mn = c >> 1, ccp = c & 1;                    \
            const u16* g = wtf + ((size_t)(mn * 32 + (p) * 2 + ccp) * 64 + lane) * 8; \
            u16* l = &Wl[buf][(size_t)(mn * 2 + ccp) * 512];                   \
            gld_lds16(g, l);                                                   \
        }                                                                      \
    }

    float4 xa[4], xb[4];
#pragma unroll
    for (int t = 0; t < 4; ++t)
        xa[t] = *(const float4a*)(xr + (t >> 1) * 32 + (t & 1) * 4);
#pragma unroll
    for (int t = 0; t < 4; ++t)
        xb[t] = *(const float4a*)(xr + (2 + (t >> 1)) * 32 + (t & 1) * 4);

    STAGE(0, 0);
    __syncthreads();

    for (int p = 0; p < 16; ++p) {
        if (p < 15) STAGE(p + 1, (p + 1) & 1);
        float4 xn[4];
        if (p < 14) {
#pragma unroll
            for (int t = 0; t < 4; ++t)
                xn[t] = *(const float4a*)(xr + (2 * (p + 2) + (t >> 1)) * 32 + (t & 1) * 4);
        }
        const u16* wb = Wl[p & 1];
#pragma unroll
        for (int ccp = 0; ccp < 2; ++ccp) {
            short8 af = cvt8(xa[ccp * 2], xa[ccp * 2 + 1]);
#pragma unroll
            for (int mn = 0; mn < 12; ++mn) {
                short8 bf = *(const short8a*)(wb + ((size_t)(mn * 2 + ccp) * 64 + lane) * 8);
                acc[mn] = __builtin_amdgcn_mfma_f32_16x16x32_bf16(af, bf, acc[mn], 0, 0, 0);
            }
        }
#pragma unroll
        for (int t = 0; t < 4; ++t) { xa[t] = xb[t]; if (p < 14) xb[t] = xn[t]; }
        __syncthreads();
    }
#undef STAGE

    const int b  = (int)(rowbase >> 12);
    const int tb = (int)(rowbase & 4095);

    // q: natural [t][h]
#pragma unroll
    for (int n = 0; n < 4; ++n)
#pragma unroll
        for (int r = 0; r < 4; ++r)
            qb[(rowbase + quad * 4 + r) * 64 + n * 16 + m] = f2bf(acc[n][r]);

    // kA[b][key>>4][h>>5][(key&15)+16*((h>>3)&3)][h&7]
#pragma unroll
    for (int n = 0; n < 4; ++n) {
        int kk = n >> 1;
        int lq = (n * 2 + (m >> 3)) & 3;
        int j  = m & 7;
#pragma unroll
        for (int r = 0; r < 4; ++r) {
            int key = tb + quad * 4 + r;
            size_t a = ((((size_t)b * 256 + (key >> 4)) * 2 + kk) * 64
                        + ((key & 15) + 16 * lq)) * 8 + j;
            kA[a] = f2bf(acc[4 + n][r]);
        }
    }

    // vA[b][h>>4][key>>5][(h&15)+16*((key>>3)&3)][key&7]
    {
        int key0 = tb + quad * 4;
        int j0 = key0 & 7;
        int q2 = (key0 >> 3) & 3;
        int kc = key0 >> 5;
#pragma unroll
        for (int n = 0; n < 4; ++n) {
            u64 pv = (u64)pk_bf(acc[8 + n][0], acc[8 + n][1])
                   | ((u64)pk_bf(acc[8 + n][2], acc[8 + n][3]) << 32);
            size_t a = ((((size_t)b * 4 + n) * 128 + kc) * 64 + (m + 16 * q2)) * 8 + j0;
            *(u64a*)(vA + a) = pv;
        }
    }
}

// ---- attention: adaptive split-K parts per 16-row strip (trivial merge w/ fixed max) ----
struct K8 { short8 k[8]; };

__device__ __forceinline__ void loadK(K8& f, const u16* kAb, int kt, int lane) {
    const u16* kp = kAb + (size_t)kt * 4096 + (size_t)lane * 8;
#pragma unroll
    for (int mt = 0; mt < 4; ++mt) {
        f.k[mt * 2]     = *(const short8a*)(kp + mt * 1024);
        f.k[mt * 2 + 1] = *(const short8a*)(kp + mt * 1024 + 512);
    }
}

__device__ __forceinline__ void attn_step(const K8& f, const u16* vAb,
        short8 qf0, short8 qf1, u16* pw,
        f32x4& o0, f32x4& o1, f32x4& o2, f32x4& o3,
        float& lsum, int kt, int n_s, int qrow, int quad, int m, int lane) {
    const float L2E = 1.4426950408889634f;
    const float FMB = 4.0f * L2E;
    // V frags: issue early (independent of S chain)
    const u16* vp = vAb + (size_t)kt * 1024 + (size_t)lane * 8;
    short8 vf[8];
#pragma unroll
    for (int ht = 0; ht < 4; ++ht) {
        vf[ht * 2]     = *(const short8a*)(vp + (size_t)ht * 65536);
        vf[ht * 2 + 1] = *(const short8a*)(vp + (size_t)ht * 65536 + 512);
    }
    f32x4 s[4];
#pragma unroll
    for (int mt = 0; mt < 4; ++mt) {
        f32x4 a = (f32x4){0.f, 0.f, 0.f, 0.f};
        a = __builtin_amdgcn_mfma_f32_16x16x32_bf16(f.k[mt * 2],     qf0, a, 0, 0, 0);
        a = __builtin_amdgcn_mfma_f32_16x16x32_bf16(f.k[mt * 2 + 1], qf1, a, 0, 0, 0);
        s[mt] = a;
    }
    if (kt == n_s) {
#pragma unroll
        for (int mt = 0; mt < 4; ++mt)
#pragma unroll
            for (int r = 0; r < 4; ++r) {
                int key = kt * 64 + mt * 16 + quad * 4 + r;
                if (key > qrow) s[mt][r] = -1e30f;
            }
    }
#pragma unroll
    for (int mt = 0; mt < 4; ++mt) {
        float p0 = __builtin_amdgcn_exp2f(s[mt][0] * L2E - FMB);
        float p1 = __builtin_amdgcn_exp2f(s[mt][1] * L2E - FMB);
        float p2 = __builtin_amdgcn_exp2f(s[mt][2] * L2E - FMB);
        float p3 = __builtin_amdgcn_exp2f(s[mt][3] * L2E - FMB);
        lsum += (p0 + p1) + (p2 + p3);
        u64 pv = (u64)pk_bf(p0, p1) | ((u64)pk_bf(p2, p3) << 32);
        *(u64a*)(pw + m * LPP + mt * 16 + quad * 4) = pv;
    }
    __builtin_amdgcn_wave_barrier();
    short8 pf0 = ld_frag_lds(pw + m * LPP + quad * 8);
    short8 pf1 = ld_frag_lds(pw + m * LPP + 32 + quad * 8);
    o0 = __builtin_amdgcn_mfma_f32_16x16x32_bf16(vf[0], pf0, o0, 0, 0, 0);
    o0 = __builtin_amdgcn_mfma_f32_16x16x32_bf16(vf[1], pf1, o0, 0, 0, 0);
    o1 = __builtin_amdgcn_mfma_f32_16x16x32_bf16(vf[2], pf0, o1, 0, 0, 0);
    o1 = __builtin_amdgcn_mfma_f32_16x16x32_bf16(vf[3], pf1, o1, 0, 0, 0);
    o2 = __builtin_amdgcn_mfma_f32_16x16x32_bf16(vf[4], pf0, o2, 0, 0, 0);
    o2 = __builtin_amdgcn_mfma_f32_16x16x32_bf16(vf[5], pf1, o2, 0, 0, 0);
    o3 = __builtin_amdgcn_mfma_f32_16x16x32_bf16(vf[6], pf0, o3, 0, 0, 0);
    o3 = __builtin_amdgcn_mfma_f32_16x16x32_bf16(vf[7], pf1, o3, 0, 0, 0);
}

__global__ __launch_bounds__(256, 3) void attn_kernel(const u16* __restrict__ qb,
                                                      const u16* __restrict__ kA,
                                                      const u16* __restrict__ vA,
                                                      float* __restrict__ out) {
    __shared__ __align__(16) u16 Pt[4][16 * LPP];
    __shared__ float Ob[4][16][64];
    __shared__ float Lb[4][64];

    const int tid = threadIdx.x, lane = tid & 63, wave = tid >> 6;
    const int m = lane & 15, quad = lane >> 4;
    const int beta = blockIdx.x;
    const int b = beta & 7, u = beta >> 3;            // u in [0,128)

    // strips: light s0=u (T0 tiles), heavy s1=255-u (T1 tiles); T0+T1 = 65
    const int T0 = (u >> 2) + 1;                      // in [1,32]
    const int T1 = 64 - (u >> 2);                     // in [33,64]
    // adaptive wave split: minimize max(ceil(T0/n0), ceil(T1/n1)) over {(1,3),(2,2)}
    const int max13 = (T0 > (T1 + 2) / 3) ? T0 : (T1 + 2) / 3;
    const int c22a = (T0 + 1) >> 1, c22b = (T1 + 1) >> 1;
    const int max22 = (c22a > c22b) ? c22a : c22b;
    const int n0 = (max13 <= max22) ? 1 : 2;
    const int n1 = 4 - n0;

    const int r = (wave + beta) & 3;                  // rotate roles across SIMDs
    const int strip_id = (r < n0) ? 0 : 1;
    const int part   = strip_id ? (r - n0) : r;
    const int nparts = strip_id ? n1 : n0;
    const int T      = strip_id ? T1 : T0;
    const int s      = strip_id ? (255 - u) : u;      // 16-row strip index
    const int qbase = s * 16;
    const int n_s = s >> 2;                           // diagonal tile
    const int kt0 = part * T / nparts;
    const int kt1 = (part + 1) * T / nparts - 1;      // inclusive; last part ends at n_s

    const u16* qp = qb + ((size_t)b * Tseq + qbase + m) * 64;
    short8 qf0 = *(const short8a*)(qp + quad * 8);
    short8 qf1 = *(const short8a*)(qp + 32 + quad * 8);

    const u16* kAb = kA + (size_t)b * (256 * 2 * 64 * 8);
    const u16* vAb = vA + (size_t)b * (4 * 128 * 64 * 8);
    u16* pw = Pt[wave];

    f32x4 o0 = {0.f, 0.f, 0.f, 0.f}, o1 = o0, o2 = o0, o3 = o0;
    float lsum = 0.f;
    const int qrow = qbase + m;

    if (kt0 <= kt1) {
        K8 ka, kb2;
        loadK(ka, kAb, kt0, lane);
        int kt = kt0;
        while (true) {
            if (kt < kt1) loadK(kb2, kAb, kt + 1, lane);
            attn_step(ka, vAb, qf0, qf1, pw, o0, o1, o2, o3, lsum,
                      kt, n_s, qrow, quad, m, lane);
            if (kt == kt1) break;
            ++kt;
            if (kt < kt1) loadK(ka, kAb, kt + 1, lane);
            attn_step(kb2, vAb, qf0, qf1, pw, o0, o1, o2, o3, lsum,
                      kt, n_s, qrow, quad, m, lane);
            if (kt == kt1) break;
            ++kt;
        }
    }

    // merge parts: fixed-max softmax -> O and l add directly.
    // parts >= 1 publish to their role slot; part 0 accumulates and finalizes.
    if (part != 0) {
        Ob[r][0][lane] = o0[0]; Ob[r][1][lane] = o0[1];
        Ob[r][2][lane] = o0[2]; Ob[r][3][lane] = o0[3];
        Ob[r][4][lane] = o1[0]; Ob[r][5][lane] = o1[1];
        Ob[r][6][lane] = o1[2]; Ob[r][7][lane] = o1[3];
        Ob[r][8][lane] = o2[0]; Ob[r][9][lane] = o2[1];
        Ob[r][10][lane] = o2[2]; Ob[r][11][lane] = o2[3];
        Ob[r][12][lane] = o3[0]; Ob[r][13][lane] = o3[1];
        Ob[r][14][lane] = o3[2]; Ob[r][15][lane] = o3[3];
        Lb[r][lane] = lsum;
    }
    __syncthreads();
    if (part == 0) {
#pragma unroll 1
        for (int pr = 1; pr < nparts; ++pr) {
            const int rr = r + pr;
            o0[0] += Ob[rr][0][lane]; o0[1] += Ob[rr][1][lane];
            o0[2] += Ob[rr][2][lane]; o0[3] += Ob[rr][3][lane];
            o1[0] += Ob[rr][4][lane]; o1[1] += Ob[rr][5][lane];
            o1[2] += Ob[rr][6][lane]; o1[3] += Ob[rr][7][lane];
            o2[0] += Ob[rr][8][lane]; o2[1] += Ob[rr][9][lane];
            o2[2] += Ob[rr][10][lane]; o2[3] += Ob[rr][11][lane];
            o3[0] += Ob[rr][12][lane]; o3[1] += Ob[rr][13][lane];
            o3[2] += Ob[rr][14][lane]; o3[3] += Ob[rr][15][lane];
            lsum += Lb[rr][lane];
        }

        lsum += __shfl_xor(lsum, 16, 64);
        lsum += __shfl_xor(lsum, 32, 64);
        float inv = 1.0f / lsum;

        float* orow = out + ((size_t)b * Tseq + qbase + m) * 64;
        float4 w;
        w.x = o0[0] * inv; w.y = o0[1] * inv; w.z = o0[2] * inv; w.w = o0[3] * inv;
        *(float4a*)(orow + 0 * 16 + quad * 4) = w;
        w.x = o1[0] * inv; w.y = o1[1] * inv; w.z = o1[2] * inv; w.w = o1[3] * inv;
        *(float4a*)(orow + 1 * 16 + quad * 4) = w;
        w.x = o2[0] * inv; w.y = o2[1] * inv; w.z = o2[2] * inv; w.w = o2[3] * inv;
        *(float4a*)(orow + 2 * 16 + quad * 4) = w;
        w.x = o3[0] * inv; w.y = o3[1] * inv; w.z = o3[2] * inv; w.w = o3[3] * inv;
        *(float4a*)(orow + 3 * 16 + quad * 4) = w;
    }
}

extern "C" void kernel_launch(void* const* d_in, const int* in_sizes, int n_in,
                              void* d_out, int out_size, void* d_ws, size_t ws_size,
                              hipStream_t stream) {
    const float* x  = (const float*)d_in[0];
    const float* Wq = (const float*)d_in[1];
    const float* Wk = (const float*)d_in[2];
    const float* Wv = (const float*)d_in[3];
    float* out = (float*)d_out;

    char* ws = (char*)d_ws;
    u16* wtf = (u16*)ws;                                       // 384 KiB
    u16* qb  = (u16*)(ws + 512 * 1024);                        // 4 MiB
    u16* kA  = (u16*)(ws + 512 * 1024 + 4 * 1024 * 1024);      // 4 MiB
    u16* vA  = (u16*)(ws + 512 * 1024 + 8 * 1024 * 1024);      // 4 MiB

    wt_kernel<<<96, 256, 0, stream>>>(Wq, Wk, Wv, wtf);
    proj_kernel<<<512, 256, 0, stream>>>(x, wtf, qb, kA, vA);
    attn_kernel<<<1024, 256, 0, stream>>>(qb, kA, vA, out);
}